// Round 7
// baseline (382.956 us; speedup 1.0000x reference)
//
#include <hip/hip_runtime.h>

typedef __attribute__((ext_vector_type(8))) __bf16 bf16x8;
typedef __attribute__((ext_vector_type(4))) float f32x4;
typedef unsigned short u16;
typedef unsigned int u32;

__device__ __forceinline__ u16 f2bf_bits(float f) {
  union { float f; u32 u; } v; v.f = f;
  u32 r = (v.u + 0x7fffu + ((v.u >> 16) & 1u)) >> 16;
  return (u16)r;
}

__device__ __forceinline__ void gload_lds16(const u16* g, u16* l) {
  __builtin_amdgcn_global_load_lds(
      (const __attribute__((address_space(1))) void*)g,
      (__attribute__((address_space(3))) void*)l, 16, 0, 0);
}

__device__ __forceinline__ bf16x8 lds_read8(const u16* base, int byteoff) {
  return *reinterpret_cast<const bf16x8*>(reinterpret_cast<const char*>(base) + byteoff);
}

// ---------------- cast fp32 -> bf16 (vectorized) ----------------
__global__ void cast_bf16_kernel(const float* __restrict__ in, u16* __restrict__ out, int n4) {
  int i = blockIdx.x * blockDim.x + threadIdx.x;
  if (i >= n4) return;
  float4 v = reinterpret_cast<const float4*>(in)[i];
  ushort4 o;
  o.x = f2bf_bits(v.x); o.y = f2bf_bits(v.y);
  o.z = f2bf_bits(v.z); o.w = f2bf_bits(v.w);
  reinterpret_cast<ushort4*>(out)[i] = o;
}

// ---------------- build per-head transposed V ----------------
__global__ void build_vt_kernel(const float* __restrict__ x, u16* __restrict__ vt, int S, int E, int H) {
  __shared__ float t[32][33];
  const int bh = blockIdx.z, b = bh / H, h = bh % H;
  const int s0 = blockIdx.x * 32, d0 = blockIdx.y * 32;
  const int tx = threadIdx.x & 31, ty = threadIdx.x >> 5;
  const float* xp = x + ((size_t)b * S) * E + (size_t)h * 128;
  #pragma unroll
  for (int r = ty; r < 32; r += 8)
    t[r][tx] = xp[(size_t)(s0 + r) * E + d0 + tx];
  __syncthreads();
  u16* vp = vt + ((size_t)bh * 128 + d0) * S + s0;
  #pragma unroll
  for (int r = ty; r < 32; r += 8)
    vp[(size_t)r * S + tx] = f2bf_bits(t[tx][r]);
}

// ---------------- pipelined GEMM: C[m,n] = sum_k A[m,k]*Bt[n,k] ----------------
// BM=128, BN=256, BK=64. 8 waves (2 wr x 4 wc), per-wave C = 64x64 (4x4 frag tiles).
// Triple-buffered LDS (144KB), stage-ahead-2 via global_load_lds, counted vmcnt(6),
// XOR-swizzled 128B LDS rows (pre-swizzled global source + swizzled reads, rule 21).
// blockIdx.z selects (B0,C0) vs (B1,C1) for fused Q+K projection.
template <bool BF16OUT>
__global__ __launch_bounds__(512) void gemm2_kernel(const u16* __restrict__ A,
                                                    const u16* __restrict__ B0,
                                                    const u16* __restrict__ B1,
                                                    void* __restrict__ C0,
                                                    void* __restrict__ C1,
                                                    int M, int N, int K) {
  __shared__ __align__(16) u16 As[3][128 * 64];
  __shared__ __align__(16) u16 Bs[3][256 * 64];
  const u16* Bt = blockIdx.z ? B1 : B0;
  void* Cout = blockIdx.z ? C1 : C0;
  const int tid = threadIdx.x;
  const int wave = tid >> 6, lane = tid & 63;
  const int lr = lane & 15, lh = lane >> 4;
  const int nbn = N >> 8;                 // N/256
  const int nwg = gridDim.x;              // divisible by 8
  const int bid = blockIdx.x;
  const int wg = (bid & 7) * (nwg >> 3) + (bid >> 3);   // XCD swizzle
  const int bm = wg / nbn, bn = wg % nbn;
  const int m0 = bm << 7, n0 = bn << 8;
  const int wr = wave >> 2, wc = wave & 3;

  const f32x4 zf = {0.f, 0.f, 0.f, 0.f};
  f32x4 acc[4][4];
  #pragma unroll
  for (int i = 0; i < 4; ++i)
    #pragma unroll
    for (int j = 0; j < 4; ++j) acc[i][j] = zf;

  // staging precompute: per gload instr, dst byte = i*8192 + tid*16 (linear);
  // global source col pre-inverse-swizzled so reads can swizzle.
  const u16* agp[2]; int adst[2];
  const u16* bgp[4]; int bdst[4];
  #pragma unroll
  for (int i = 0; i < 2; ++i) {
    const int db = i * 8192 + tid * 16;
    const int row = db >> 7;
    const int cb = (db & 127) ^ ((row & 7) << 4);
    agp[i] = A + (size_t)(m0 + row) * K + (cb >> 1);
    adst[i] = (i * 8192 + wave * 1024) >> 1;          // wave-uniform LDS base (u16 idx)
  }
  #pragma unroll
  for (int i = 0; i < 4; ++i) {
    const int db = i * 8192 + tid * 16;
    const int row = db >> 7;
    const int cb = (db & 127) ^ ((row & 7) << 4);
    bgp[i] = Bt + (size_t)(n0 + row) * K + (cb >> 1);
    bdst[i] = (i * 8192 + wave * 1024) >> 1;
  }

  const int NT = K >> 6;   // K/64 tiles

  // prologue: stage tiles 0 -> buf0, 1 -> buf1 (12 issues); wait oldest 6 (tile 0)
  #pragma unroll
  for (int i = 0; i < 2; ++i) gload_lds16(agp[i], &As[0][adst[i]]);
  #pragma unroll
  for (int i = 0; i < 4; ++i) gload_lds16(bgp[i], &Bs[0][bdst[i]]);
  #pragma unroll
  for (int i = 0; i < 2; ++i) gload_lds16(agp[i] + 64, &As[1][adst[i]]);
  #pragma unroll
  for (int i = 0; i < 4; ++i) gload_lds16(bgp[i] + 64, &Bs[1][bdst[i]]);
  asm volatile("s_waitcnt vmcnt(6)" ::: "memory");
  __builtin_amdgcn_sched_barrier(0);
  __builtin_amdgcn_s_barrier();

  for (int t = 0; t < NT; ++t) {
    const int cur = t % 3;
    // stage tile t+2 into buf (t+2)%3 (read last in iter t-1: WAR-safe past prev barrier)
    if (t + 2 < NT) {
      const int sb = (t + 2) % 3;
      const int k0 = (t + 2) << 6;
      #pragma unroll
      for (int i = 0; i < 2; ++i) gload_lds16(agp[i] + k0, &As[sb][adst[i]]);
      #pragma unroll
      for (int i = 0; i < 4; ++i) gload_lds16(bgp[i] + k0, &Bs[sb][bdst[i]]);
    }
    // ds_read all fragments of tile t (swizzled reads)
    bf16x8 af[4][2], bfv[4][2];
    #pragma unroll
    for (int i = 0; i < 4; ++i) {
      #pragma unroll
      for (int s = 0; s < 2; ++s) {
        const int rowA = wr * 64 + i * 16 + lr;
        af[i][s] = lds_read8(As[cur], rowA * 128 + ((s * 64 + lh * 16) ^ ((rowA & 7) << 4)));
        const int rowB = wc * 64 + i * 16 + lr;
        bfv[i][s] = lds_read8(Bs[cur], rowB * 128 + ((s * 64 + lh * 16) ^ ((rowB & 7) << 4)));
      }
    }
    __builtin_amdgcn_s_setprio(1);
    #pragma unroll
    for (int s = 0; s < 2; ++s)
      #pragma unroll
      for (int i = 0; i < 4; ++i)
        #pragma unroll
        for (int j = 0; j < 4; ++j)
          acc[i][j] = __builtin_amdgcn_mfma_f32_16x16x32_bf16(af[i][s], bfv[j][s], acc[i][j], 0, 0, 0);
    __builtin_amdgcn_s_setprio(0);
    // drain own ds_reads (WAR vs next stage) + counted vmem wait (RAW for tile t+1)
    asm volatile("s_waitcnt lgkmcnt(0)" ::: "memory");
    if (t + 2 < NT) {
      asm volatile("s_waitcnt vmcnt(6)" ::: "memory");
    } else {
      asm volatile("s_waitcnt vmcnt(0)" ::: "memory");
    }
    __builtin_amdgcn_sched_barrier(0);
    __builtin_amdgcn_s_barrier();
  }

  // epilogue: C row = lh*4 + reg, col = lr within each 16x16 tile
  #pragma unroll
  for (int i = 0; i < 4; ++i) {
    const int row0 = m0 + wr * 64 + i * 16 + lh * 4;
    #pragma unroll
    for (int j = 0; j < 4; ++j) {
      const int col = n0 + wc * 64 + j * 16 + lr;
      #pragma unroll
      for (int r = 0; r < 4; ++r) {
        const size_t idx = (size_t)(row0 + r) * N + col;
        if (BF16OUT)
          ((u16*)Cout)[idx] = f2bf_bits(acc[i][j][r]);
        else
          ((float*)Cout)[idx] = acc[i][j][r];
      }
    }
  }
}

// ---------------- flash attention v3: LDS-staged K/V + no-max softmax ----------------
__global__ __launch_bounds__(256, 4) void attn_kernel(const u16* __restrict__ Q,
                                                      const u16* __restrict__ Kx,
                                                      const u16* __restrict__ Vt,
                                                      u16* __restrict__ O,
                                                      int S, int E, int H) {
  __shared__ __align__(16) u16 Ks[64 * 128];
  __shared__ __align__(16) u16 Vs[128 * 64];
  __shared__ __align__(16) u16 Pl[4][16 * 64];

  const int tid = threadIdx.x;
  const int wave = tid >> 6, lane = tid & 63;
  const int lr = lane & 15, lh = lane >> 4;
  const int qb = blockIdx.x;
  const int bh = blockIdx.y;
  const int b = bh / H, h = bh % H;
  const size_t base = ((size_t)b * S) * E + (size_t)h * 128;
  const u16* Qp = Q + base;
  const u16* Kp = Kx + base;
  const u16* Vp = Vt + (size_t)bh * 128 * S;
  u16* Op = O + base;

  const int qrow = qb * 64 + wave * 16 + lr;
  bf16x8 qf[4];
  #pragma unroll
  for (int c = 0; c < 4; ++c)
    qf[c] = *reinterpret_cast<const bf16x8*>(Qp + (size_t)qrow * E + c * 32 + lh * 8);

  const int dstb = wave * 1024 + lane * 16;
  int ksrc[4], vsrc[4];
  u16 *kdst[4], *vdst[4];
  #pragma unroll
  for (int i = 0; i < 4; ++i) {
    const int db = dstb + i * 4096;
    const int s = db >> 8;
    const int kcb = (db & 255) ^ ((s & 7) << 4);
    ksrc[i] = s * E + (kcb >> 1);
    kdst[i] = Ks + ((wave * 1024 + i * 4096) >> 1);
    const int d = db >> 7;
    const int vcb = (db & 127) ^ ((d & 7) << 4);
    vsrc[i] = d * S + (vcb >> 1);
    vdst[i] = Vs + ((wave * 1024 + i * 4096) >> 1);
  }

  const f32x4 zf = {0.f, 0.f, 0.f, 0.f};
  f32x4 oacc[8];
  #pragma unroll
  for (int n = 0; n < 8; ++n) oacc[n] = zf;
  float Lp[4] = {0.f, 0.f, 0.f, 0.f};

  const float c2 = 0.12751649736230842f;  // log2(e)/sqrt(128)
  const int swz = (lr & 7) << 4;
  u16* pw = &Pl[wave][0];

  for (int s0 = 0; s0 < S; s0 += 64) {
    #pragma unroll
    for (int i = 0; i < 4; ++i) gload_lds16(Kp + s0 * E + ksrc[i], kdst[i]);
    #pragma unroll
    for (int i = 0; i < 4; ++i) gload_lds16(Vp + s0 + vsrc[i], vdst[i]);
    __syncthreads();

    f32x4 sg[4];
    #pragma unroll
    for (int g = 0; g < 4; ++g) sg[g] = zf;
    #pragma unroll
    for (int c = 0; c < 4; ++c) {
      const int cb = (c * 64 + lh * 16) ^ swz;
      #pragma unroll
      for (int g = 0; g < 4; ++g) {
        bf16x8 kf = lds_read8(Ks, (g * 16 + lr) * 256 + cb);
        sg[g] = __builtin_amdgcn_mfma_f32_16x16x32_bf16(qf[c], kf, sg[g], 0, 0, 0);
      }
    }

    float p[4][4];
    #pragma unroll
    for (int g = 0; g < 4; ++g)
      #pragma unroll
      for (int j = 0; j < 4; ++j)
        p[g][j] = __builtin_exp2f(sg[g][j] * c2);
    #pragma unroll
    for (int j = 0; j < 4; ++j)
      Lp[j] += (p[0][j] + p[1][j]) + (p[2][j] + p[3][j]);

    #pragma unroll
    for (int j = 0; j < 4; ++j) {
      const int r = lh * 4 + j;
      const int rx = (r & 7) << 4;
      #pragma unroll
      for (int g = 0; g < 4; ++g) {
        const int cbp = ((g * 16 + lr) * 2) ^ rx;
        *reinterpret_cast<u16*>(reinterpret_cast<char*>(pw) + r * 128 + cbp) = f2bf_bits(p[g][j]);
      }
    }

    #pragma unroll
    for (int ks = 0; ks < 2; ++ks) {
      const int cb = ks * 64 + lh * 16;
      bf16x8 pf = lds_read8(pw, lr * 128 + (cb ^ swz));
      #pragma unroll
      for (int n = 0; n < 8; ++n) {
        bf16x8 vf = lds_read8(Vs, (n * 16 + lr) * 128 + (cb ^ swz));
        oacc[n] = __builtin_amdgcn_mfma_f32_16x16x32_bf16(pf, vf, oacc[n], 0, 0, 0);
      }
    }
    __syncthreads();
  }

  #pragma unroll
  for (int m = 1; m <= 8; m <<= 1)
    #pragma unroll
    for (int j = 0; j < 4; ++j)
      Lp[j] += __shfl_xor(Lp[j], m, 64);

  float inv[4];
  #pragma unroll
  for (int j = 0; j < 4; ++j) inv[j] = 1.0f / Lp[j];
  const int orow0 = qb * 64 + wave * 16 + lh * 4;
  #pragma unroll
  for (int n = 0; n < 8; ++n)
    #pragma unroll
    for (int j = 0; j < 4; ++j)
      Op[(size_t)(orow0 + j) * E + n * 16 + lr] = f2bf_bits(oacc[n][j] * inv[j]);
}

extern "C" void kernel_launch(void* const* d_in, const int* in_sizes, int n_in,
                              void* d_out, int out_size, void* d_ws, size_t ws_size,
                              hipStream_t stream) {
  const float* x    = (const float*)d_in[0];
  const float* rot  = (const float*)d_in[1];
  const float* ent  = (const float*)d_in[2];
  const float* wout = (const float*)d_in[3];
  const int B = 2, S = 2048, E = 2048, H = 16;
  const int M = B * S;                 // 4096
  const size_t nBSE = (size_t)M * E;   // 16 MB as bf16
  const size_t nEE = (size_t)E * E;    // 8 MB as bf16

  // ws: 3*nBSE u16 = 48 MB
  u16* xb = (u16*)d_ws;        // bf16 x; reused as ob after QK GEMM
  u16* qb = xb + nBSE;
  u16* kb = qb + nBSE;         // reused for bf16 w_out after attention
  // d_out (32 MB) as scratch until final GEMM: rb(8) + eb(8) + vt(16)
  u16* rb = (u16*)d_out;
  u16* eb = rb + nEE;
  u16* vt = eb + nEE;
  u16* wb = kb;
  u16* ob = xb;

  cast_bf16_kernel<<<(int)(nBSE / 4 / 256), 256, 0, stream>>>(x, xb, (int)(nBSE / 4));
  cast_bf16_kernel<<<(int)(nEE / 4 / 256), 256, 0, stream>>>(rot, rb, (int)(nEE / 4));
  cast_bf16_kernel<<<(int)(nEE / 4 / 256), 256, 0, stream>>>(ent, eb, (int)(nEE / 4));

  dim3 tg(S / 32, 128 / 32, B * H);
  build_vt_kernel<<<tg, 256, 0, stream>>>(x, vt, S, E, H);

  // fused Q+K projection (z=0 -> Q=A.R^T, z=1 -> K=A.E^T)
  const int g2 = (M / 128) * (E / 256);   // 256 blocks per z
  gemm2_kernel<true><<<dim3(g2, 1, 2), 512, 0, stream>>>(xb, rb, eb, qb, kb, M, E, E);

  dim3 ag(S / 64, B * H);
  attn_kernel<<<ag, 256, 0, stream>>>(qb, kb, vt, ob, S, E, H);

  cast_bf16_kernel<<<(int)(nEE / 4 / 256), 256, 0, stream>>>(wout, wb, (int)(nEE / 4));

  // output projection (fp32 out)
  gemm2_kernel<false><<<dim3(g2, 1, 1), 512, 0, stream>>>(ob, wb, wb, d_out, d_out, M, E, E);
}

// Round 8
// 375.948 us; speedup vs baseline: 1.0186x; 1.0186x over previous
//
#include <hip/hip_runtime.h>

typedef __attribute__((ext_vector_type(8))) __bf16 bf16x8;
typedef __attribute__((ext_vector_type(4))) float f32x4;
typedef unsigned short u16;
typedef unsigned int u32;

__device__ __forceinline__ u16 f2bf_bits(float f) {
  __bf16 h = (__bf16)f;           // native RNE cvt (v_cvt_pk_bf16_f32 path)
  u16 r;
  __builtin_memcpy(&r, &h, 2);
  return r;
}

__device__ __forceinline__ void gload_lds16(const u16* g, u16* l) {
  __builtin_amdgcn_global_load_lds(
      (const __attribute__((address_space(1))) void*)g,
      (__attribute__((address_space(3))) void*)l, 16, 0, 0);
}

__device__ __forceinline__ bf16x8 lds_read8(const u16* base, int byteoff) {
  return *reinterpret_cast<const bf16x8*>(reinterpret_cast<const char*>(base) + byteoff);
}

// ---------------- cast fp32 -> bf16 (vectorized) ----------------
__global__ void cast_bf16_kernel(const float* __restrict__ in, u16* __restrict__ out, int n4) {
  int i = blockIdx.x * blockDim.x + threadIdx.x;
  if (i >= n4) return;
  float4 v = reinterpret_cast<const float4*>(in)[i];
  ushort4 o;
  o.x = f2bf_bits(v.x); o.y = f2bf_bits(v.y);
  o.z = f2bf_bits(v.z); o.w = f2bf_bits(v.w);
  reinterpret_cast<ushort4*>(out)[i] = o;
}

// ---------------- build per-head transposed V ----------------
__global__ void build_vt_kernel(const float* __restrict__ x, u16* __restrict__ vt, int S, int E, int H) {
  __shared__ float t[32][33];
  const int bh = blockIdx.z, b = bh / H, h = bh % H;
  const int s0 = blockIdx.x * 32, d0 = blockIdx.y * 32;
  const int tx = threadIdx.x & 31, ty = threadIdx.x >> 5;
  const float* xp = x + ((size_t)b * S) * E + (size_t)h * 128;
  #pragma unroll
  for (int r = ty; r < 32; r += 8)
    t[r][tx] = xp[(size_t)(s0 + r) * E + d0 + tx];
  __syncthreads();
  u16* vp = vt + ((size_t)bh * 128 + d0) * S + s0;
  #pragma unroll
  for (int r = ty; r < 32; r += 8)
    vp[(size_t)r * S + tx] = f2bf_bits(t[tx][r]);
}

// ---------------- L2-clustered GEMM: C[m,n] = sum_k A[m,k]*Bt[n,k] ----------------
// BM=BN=256, BK=64, 8 waves (2 wr x 4 wc), per-wave C = 128x64 (8x4 frag tiles).
// Double-buffered LDS (128KB), 2-phase loop (stage t+1 while computing t, __syncthreads).
// XOR-swizzled 128B LDS rows (pre-swizzled global source, rule 21).
// XCD cluster swizzle: bid&7 -> 4x4 tile cluster; Q/K jobs on adjacent slots share A panels,
// so each XCD's concurrent K-slice working set (~384KB) is L2-resident.
template <bool BF16OUT>
__global__ __launch_bounds__(512, 2) void gemm3_kernel(const u16* __restrict__ A,
                                                       const u16* __restrict__ B0,
                                                       const u16* __restrict__ B1,
                                                       void* __restrict__ C0,
                                                       void* __restrict__ C1,
                                                       int K, int N, int zmask) {
  __shared__ __align__(16) u16 As[2][256 * 64];
  __shared__ __align__(16) u16 Bs[2][256 * 64];
  const int tid = threadIdx.x;
  const int wave = tid >> 6, lane = tid & 63;
  const int lr = lane & 15, lh = lane >> 4;
  const int bid = blockIdx.x;
  const int xcd = bid & 7;
  const int slot = bid >> 3;
  const int z = slot & zmask;                 // job select (Q vs K); 0 when zmask=0
  const int c = zmask ? (slot >> 1) : slot;   // position within cluster (0..15)
  const int bm = (xcd >> 1) * 4 + (c >> 2);   // 16 bm x 8 bn grid of 256^2 tiles
  const int bn = (xcd & 1) * 4 + (c & 3);
  const int m0 = bm << 8, n0 = bn << 8;
  const u16* Bt = z ? B1 : B0;
  void* Cout = z ? C1 : C0;
  const int wr = wave >> 2, wc = wave & 3;

  const f32x4 zf = {0.f, 0.f, 0.f, 0.f};
  f32x4 acc[8][4];
  #pragma unroll
  for (int i = 0; i < 8; ++i)
    #pragma unroll
    for (int j = 0; j < 4; ++j) acc[i][j] = zf;

  // staging: 4 gload instrs per operand per tile; dst byte = i*8192 + tid*16 (linear);
  // global source col pre-inverse-swizzled so reads can swizzle.
  const u16* agp[4]; const u16* bgp[4]; int ldst[4];
  #pragma unroll
  for (int i = 0; i < 4; ++i) {
    const int db = i * 8192 + tid * 16;
    const int row = db >> 7;                      // 128B rows (64 bf16)
    const int cb = (db & 127) ^ ((row & 7) << 4); // involution
    agp[i] = A + (size_t)(m0 + row) * K + (cb >> 1);
    bgp[i] = Bt + (size_t)(n0 + row) * K + (cb >> 1);
    ldst[i] = (i * 8192 + wave * 1024) >> 1;      // wave-uniform LDS base (u16 idx)
  }

  const int NT = K >> 6;

  // prologue: tile 0 -> buf 0
  #pragma unroll
  for (int i = 0; i < 4; ++i) gload_lds16(agp[i], &As[0][ldst[i]]);
  #pragma unroll
  for (int i = 0; i < 4; ++i) gload_lds16(bgp[i], &Bs[0][ldst[i]]);
  __syncthreads();

  int cur = 0;
  for (int t = 0; t < NT; ++t) {
    // stage tile t+1 into other buffer (WAR-safe: it was drained before prev barrier)
    if (t + 1 < NT) {
      const int k0 = (t + 1) << 6;
      #pragma unroll
      for (int i = 0; i < 4; ++i) gload_lds16(agp[i] + k0, &As[cur ^ 1][ldst[i]]);
      #pragma unroll
      for (int i = 0; i < 4; ++i) gload_lds16(bgp[i] + k0, &Bs[cur ^ 1][ldst[i]]);
    }
    // B fragments (8 reads), then per-i A fragments + MFMA
    bf16x8 bfr[4][2];
    #pragma unroll
    for (int j = 0; j < 4; ++j) {
      const int rowB = wc * 64 + j * 16 + lr;
      #pragma unroll
      for (int ks = 0; ks < 2; ++ks)
        bfr[j][ks] = lds_read8(Bs[cur], rowB * 128 + ((ks * 64 + lh * 16) ^ ((rowB & 7) << 4)));
    }
    __builtin_amdgcn_s_setprio(1);
    #pragma unroll
    for (int i = 0; i < 8; ++i) {
      const int rowA = wr * 128 + i * 16 + lr;
      bf16x8 af0 = lds_read8(As[cur], rowA * 128 + ((lh * 16) ^ ((rowA & 7) << 4)));
      bf16x8 af1 = lds_read8(As[cur], rowA * 128 + ((64 + lh * 16) ^ ((rowA & 7) << 4)));
      #pragma unroll
      for (int j = 0; j < 4; ++j) {
        acc[i][j] = __builtin_amdgcn_mfma_f32_16x16x32_bf16(af0, bfr[j][0], acc[i][j], 0, 0, 0);
        acc[i][j] = __builtin_amdgcn_mfma_f32_16x16x32_bf16(af1, bfr[j][1], acc[i][j], 0, 0, 0);
      }
    }
    __builtin_amdgcn_s_setprio(0);
    __syncthreads();   // emits vmcnt(0) lgkmcnt(0) drain + barrier (proven m97 semantics)
    cur ^= 1;
  }

  // epilogue
  #pragma unroll
  for (int i = 0; i < 8; ++i) {
    const int row0 = m0 + wr * 128 + i * 16 + lh * 4;
    #pragma unroll
    for (int j = 0; j < 4; ++j) {
      const int col = n0 + wc * 64 + j * 16 + lr;
      #pragma unroll
      for (int r = 0; r < 4; ++r) {
        const size_t idx = (size_t)(row0 + r) * N + col;
        if (BF16OUT)
          ((u16*)Cout)[idx] = f2bf_bits(acc[i][j][r]);
        else
          ((float*)Cout)[idx] = acc[i][j][r];
      }
    }
  }
}

// ---------------- flash attention v3: LDS-staged K/V + no-max softmax ----------------
__global__ __launch_bounds__(256, 4) void attn_kernel(const u16* __restrict__ Q,
                                                      const u16* __restrict__ Kx,
                                                      const u16* __restrict__ Vt,
                                                      u16* __restrict__ O,
                                                      int S, int E, int H) {
  __shared__ __align__(16) u16 Ks[64 * 128];
  __shared__ __align__(16) u16 Vs[128 * 64];
  __shared__ __align__(16) u16 Pl[4][16 * 64];

  const int tid = threadIdx.x;
  const int wave = tid >> 6, lane = tid & 63;
  const int lr = lane & 15, lh = lane >> 4;
  const int qb = blockIdx.x;
  const int bh = blockIdx.y;
  const int b = bh / H, h = bh % H;
  const size_t base = ((size_t)b * S) * E + (size_t)h * 128;
  const u16* Qp = Q + base;
  const u16* Kp = Kx + base;
  const u16* Vp = Vt + (size_t)bh * 128 * S;
  u16* Op = O + base;

  const int qrow = qb * 64 + wave * 16 + lr;
  bf16x8 qf[4];
  #pragma unroll
  for (int c = 0; c < 4; ++c)
    qf[c] = *reinterpret_cast<const bf16x8*>(Qp + (size_t)qrow * E + c * 32 + lh * 8);

  const int dstb = wave * 1024 + lane * 16;
  int ksrc[4], vsrc[4];
  u16 *kdst[4], *vdst[4];
  #pragma unroll
  for (int i = 0; i < 4; ++i) {
    const int db = dstb + i * 4096;
    const int s = db >> 8;
    const int kcb = (db & 255) ^ ((s & 7) << 4);
    ksrc[i] = s * E + (kcb >> 1);
    kdst[i] = Ks + ((wave * 1024 + i * 4096) >> 1);
    const int d = db >> 7;
    const int vcb = (db & 127) ^ ((d & 7) << 4);
    vsrc[i] = d * S + (vcb >> 1);
    vdst[i] = Vs + ((wave * 1024 + i * 4096) >> 1);
  }

  const f32x4 zf = {0.f, 0.f, 0.f, 0.f};
  f32x4 oacc[8];
  #pragma unroll
  for (int n = 0; n < 8; ++n) oacc[n] = zf;
  float Lp[4] = {0.f, 0.f, 0.f, 0.f};

  const float c2 = 0.12751649736230842f;  // log2(e)/sqrt(128)
  const int swz = (lr & 7) << 4;
  u16* pw = &Pl[wave][0];

  for (int s0 = 0; s0 < S; s0 += 64) {
    #pragma unroll
    for (int i = 0; i < 4; ++i) gload_lds16(Kp + s0 * E + ksrc[i], kdst[i]);
    #pragma unroll
    for (int i = 0; i < 4; ++i) gload_lds16(Vp + s0 + vsrc[i], vdst[i]);
    __syncthreads();

    f32x4 sg[4];
    #pragma unroll
    for (int g = 0; g < 4; ++g) sg[g] = zf;
    __builtin_amdgcn_s_setprio(1);
    #pragma unroll
    for (int c = 0; c < 4; ++c) {
      const int cb = (c * 64 + lh * 16) ^ swz;
      #pragma unroll
      for (int g = 0; g < 4; ++g) {
        bf16x8 kf = lds_read8(Ks, (g * 16 + lr) * 256 + cb);
        sg[g] = __builtin_amdgcn_mfma_f32_16x16x32_bf16(qf[c], kf, sg[g], 0, 0, 0);
      }
    }
    __builtin_amdgcn_s_setprio(0);

    float p[4][4];
    #pragma unroll
    for (int g = 0; g < 4; ++g)
      #pragma unroll
      for (int j = 0; j < 4; ++j)
        p[g][j] = __builtin_exp2f(sg[g][j] * c2);
    #pragma unroll
    for (int j = 0; j < 4; ++j)
      Lp[j] += (p[0][j] + p[1][j]) + (p[2][j] + p[3][j]);

    #pragma unroll
    for (int j = 0; j < 4; ++j) {
      const int r = lh * 4 + j;
      const int rx = (r & 7) << 4;
      #pragma unroll
      for (int g = 0; g < 4; ++g) {
        const int cbp = ((g * 16 + lr) * 2) ^ rx;
        *reinterpret_cast<u16*>(reinterpret_cast<char*>(pw) + r * 128 + cbp) = f2bf_bits(p[g][j]);
      }
    }

    #pragma unroll
    for (int ks = 0; ks < 2; ++ks) {
      const int cb = ks * 64 + lh * 16;
      bf16x8 pf = lds_read8(pw, lr * 128 + (cb ^ swz));
      __builtin_amdgcn_s_setprio(1);
      #pragma unroll
      for (int n = 0; n < 8; ++n) {
        bf16x8 vf = lds_read8(Vs, (n * 16 + lr) * 128 + (cb ^ swz));
        oacc[n] = __builtin_amdgcn_mfma_f32_16x16x32_bf16(pf, vf, oacc[n], 0, 0, 0);
      }
      __builtin_amdgcn_s_setprio(0);
    }
    __syncthreads();
  }

  #pragma unroll
  for (int m = 1; m <= 8; m <<= 1)
    #pragma unroll
    for (int j = 0; j < 4; ++j)
      Lp[j] += __shfl_xor(Lp[j], m, 64);

  float inv[4];
  #pragma unroll
  for (int j = 0; j < 4; ++j) inv[j] = 1.0f / Lp[j];
  const int orow0 = qb * 64 + wave * 16 + lh * 4;
  #pragma unroll
  for (int n = 0; n < 8; ++n)
    #pragma unroll
    for (int j = 0; j < 4; ++j)
      Op[(size_t)(orow0 + j) * E + n * 16 + lr] = f2bf_bits(oacc[n][j] * inv[j]);
}

extern "C" void kernel_launch(void* const* d_in, const int* in_sizes, int n_in,
                              void* d_out, int out_size, void* d_ws, size_t ws_size,
                              hipStream_t stream) {
  const float* x    = (const float*)d_in[0];
  const float* rot  = (const float*)d_in[1];
  const float* ent  = (const float*)d_in[2];
  const float* wout = (const float*)d_in[3];
  const int B = 2, S = 2048, E = 2048, H = 16;
  const int M = B * S;                 // 4096
  const size_t nBSE = (size_t)M * E;   // 16 MB as bf16
  const size_t nEE = (size_t)E * E;    // 8 MB as bf16

  // ws: 3*nBSE u16 = 48 MB
  u16* xb = (u16*)d_ws;        // bf16 x; reused as ob after QK GEMM
  u16* qb = xb + nBSE;
  u16* kb = qb + nBSE;         // reused for bf16 w_out after attention
  // d_out (32 MB) as scratch until final GEMM: rb(8) + eb(8) + vt(16)
  u16* rb = (u16*)d_out;
  u16* eb = rb + nEE;
  u16* vt = eb + nEE;
  u16* wb = kb;
  u16* ob = xb;

  cast_bf16_kernel<<<(int)(nBSE / 4 / 256), 256, 0, stream>>>(x, xb, (int)(nBSE / 4));
  cast_bf16_kernel<<<(int)(nEE / 4 / 256), 256, 0, stream>>>(rot, rb, (int)(nEE / 4));
  cast_bf16_kernel<<<(int)(nEE / 4 / 256), 256, 0, stream>>>(ent, eb, (int)(nEE / 4));

  dim3 tg(S / 32, 128 / 32, B * H);
  build_vt_kernel<<<tg, 256, 0, stream>>>(x, vt, S, E, H);

  // fused Q+K projection: 256 wgs = 8 XCD clusters x 16 positions x 2 jobs (zmask=1)
  gemm3_kernel<true><<<256, 512, 0, stream>>>(xb, rb, eb, qb, kb, E, E, 1);

  dim3 ag(S / 64, B * H);
  attn_kernel<<<ag, 256, 0, stream>>>(qb, kb, vt, ob, S, E, H);

  cast_bf16_kernel<<<(int)(nEE / 4 / 256), 256, 0, stream>>>(wout, wb, (int)(nEE / 4));

  // output projection: 128 wgs = 8 clusters x 16 positions (zmask=0), fp32 out
  gemm3_kernel<false><<<128, 512, 0, stream>>>(ob, wb, wb, d_out, d_out, E, E, 0);
}

// Round 10
// 374.353 us; speedup vs baseline: 1.0230x; 1.0043x over previous
//
#include <hip/hip_runtime.h>

typedef __attribute__((ext_vector_type(8))) __bf16 bf16x8;
typedef __attribute__((ext_vector_type(4))) float f32x4;
typedef unsigned short u16;
typedef unsigned int u32;

__device__ __forceinline__ u16 f2bf_bits(float f) {
  __bf16 h = (__bf16)f;           // native RNE cvt
  u16 r;
  __builtin_memcpy(&r, &h, 2);
  return r;
}

__device__ __forceinline__ void gload_lds16(const u16* g, u16* l) {
  __builtin_amdgcn_global_load_lds(
      (const __attribute__((address_space(1))) void*)g,
      (__attribute__((address_space(3))) void*)l, 16, 0, 0);
}

__device__ __forceinline__ bf16x8 lds_read8(const u16* base, int byteoff) {
  return *reinterpret_cast<const bf16x8*>(reinterpret_cast<const char*>(base) + byteoff);
}

// ---------------- cast fp32 -> bf16 (vectorized) ----------------
__global__ void cast_bf16_kernel(const float* __restrict__ in, u16* __restrict__ out, int n4) {
  int i = blockIdx.x * blockDim.x + threadIdx.x;
  if (i >= n4) return;
  float4 v = reinterpret_cast<const float4*>(in)[i];
  ushort4 o;
  o.x = f2bf_bits(v.x); o.y = f2bf_bits(v.y);
  o.z = f2bf_bits(v.z); o.w = f2bf_bits(v.w);
  reinterpret_cast<ushort4*>(out)[i] = o;
}

// ---------------- build per-head transposed V ----------------
__global__ void build_vt_kernel(const float* __restrict__ x, u16* __restrict__ vt, int S, int E, int H) {
  __shared__ float t[32][33];
  const int bh = blockIdx.z, b = bh / H, h = bh % H;
  const int s0 = blockIdx.x * 32, d0 = blockIdx.y * 32;
  const int tx = threadIdx.x & 31, ty = threadIdx.x >> 5;
  const float* xp = x + ((size_t)b * S) * E + (size_t)h * 128;
  #pragma unroll
  for (int r = ty; r < 32; r += 8)
    t[r][tx] = xp[(size_t)(s0 + r) * E + d0 + tx];
  __syncthreads();
  u16* vp = vt + ((size_t)bh * 128 + d0) * S + s0;
  #pragma unroll
  for (int r = ty; r < 32; r += 8)
    vp[(size_t)r * S + tx] = f2bf_bits(t[tx][r]);
}

// ---------------- L2-clustered GEMM: C[m,n] = sum_k A[m,k]*Bt[n,k] ----------------
// BM x 256 tiles, BK=64, 8 waves (2 wr x 4 wc), per-wave C = (BM/2)x64.
// Double-buffered LDS, 2-phase loop (stage t+1 issued before compute t, one sync/iter).
// XOR-swizzled 128B LDS rows (pre-swizzled global source, rule 21).
// BM=256: QK fused (zmask=1, 256 wgs, 16x8 tile grid per job).
// BM=128: out-proj (zmask=0, 256 wgs, 32x8 tile grid) -- full chip.
template <bool BF16OUT, int BM>
__global__ __launch_bounds__(512, 2) void gemm3_kernel(const u16* __restrict__ A,
                                                       const u16* __restrict__ B0,
                                                       const u16* __restrict__ B1,
                                                       void* __restrict__ C0,
                                                       void* __restrict__ C1,
                                                       int K, int N, int zmask) {
  constexpr int IR = BM / 32;     // A frag tiles per wave (8 or 4)
  constexpr int ALD = BM / 64;    // A gload instrs per tile (4 or 2)
  __shared__ __align__(16) u16 As[2][BM * 64];
  __shared__ __align__(16) u16 Bs[2][256 * 64];
  const int tid = threadIdx.x;
  const int wave = tid >> 6, lane = tid & 63;
  const int lr = lane & 15, lh = lane >> 4;
  const int bid = blockIdx.x;
  const int xcd = bid & 7;
  const int slot = bid >> 3;
  int z, bm, bn;
  if (BM == 256) {
    z = slot & zmask;                         // job select (Q vs K)
    const int c = zmask ? (slot >> 1) : slot; // position within cluster (0..15)
    bm = (xcd >> 1) * 4 + (c >> 2);           // 16 bm x 8 bn grid
    bn = (xcd & 1) * 4 + (c & 3);
  } else {
    z = 0;
    bm = (xcd >> 1) * 8 + (slot >> 2);        // 32 bm x 8 bn grid
    bn = (xcd & 1) * 4 + (slot & 3);
  }
  const int m0 = bm * BM, n0 = bn << 8;
  const u16* Bt = z ? B1 : B0;
  void* Cout = z ? C1 : C0;
  const int wr = wave >> 2, wc = wave & 3;

  const f32x4 zf = {0.f, 0.f, 0.f, 0.f};
  f32x4 acc[IR][4];
  #pragma unroll
  for (int i = 0; i < IR; ++i)
    #pragma unroll
    for (int j = 0; j < 4; ++j) acc[i][j] = zf;

  // staging: dst byte = i*8192 + tid*16 (linear); global source col pre-inverse-swizzled.
  const u16* agp[ALD]; const u16* bgp[4]; int ldst[4];
  #pragma unroll
  for (int i = 0; i < 4; ++i) {
    const int db = i * 8192 + tid * 16;
    const int row = db >> 7;                      // 128B rows (64 bf16)
    const int cb = (db & 127) ^ ((row & 7) << 4); // involution
    if (i < ALD) agp[i] = A + (size_t)(m0 + row) * K + (cb >> 1);
    bgp[i] = Bt + (size_t)(n0 + row) * K + (cb >> 1);
    ldst[i] = (i * 8192 + wave * 1024) >> 1;      // wave-uniform LDS base (u16 idx)
  }

  const int NT = K >> 6;

  // prologue: tile 0 -> buf 0
  #pragma unroll
  for (int i = 0; i < ALD; ++i) gload_lds16(agp[i], &As[0][ldst[i]]);
  #pragma unroll
  for (int i = 0; i < 4; ++i) gload_lds16(bgp[i], &Bs[0][ldst[i]]);

  int cur = 0;
  for (int t = 0; t < NT; ++t) {
    __syncthreads();   // drains vmcnt(0): tile t staged; prev compute done (WAR safe)
    if (t + 1 < NT) {
      const int k0 = (t + 1) << 6;
      #pragma unroll
      for (int i = 0; i < ALD; ++i) gload_lds16(agp[i] + k0, &As[cur ^ 1][ldst[i]]);
      #pragma unroll
      for (int i = 0; i < 4; ++i) gload_lds16(bgp[i] + k0, &Bs[cur ^ 1][ldst[i]]);
    }
    bf16x8 bfr[4][2];
    #pragma unroll
    for (int j = 0; j < 4; ++j) {
      const int rowB = wc * 64 + j * 16 + lr;
      #pragma unroll
      for (int ks = 0; ks < 2; ++ks)
        bfr[j][ks] = lds_read8(Bs[cur], rowB * 128 + ((ks * 64 + lh * 16) ^ ((rowB & 7) << 4)));
    }
    __builtin_amdgcn_s_setprio(1);
    #pragma unroll
    for (int i = 0; i < IR; ++i) {
      const int rowA = wr * (BM / 2) + i * 16 + lr;
      bf16x8 af0 = lds_read8(As[cur], rowA * 128 + ((lh * 16) ^ ((rowA & 7) << 4)));
      bf16x8 af1 = lds_read8(As[cur], rowA * 128 + ((64 + lh * 16) ^ ((rowA & 7) << 4)));
      #pragma unroll
      for (int j = 0; j < 4; ++j) {
        acc[i][j] = __builtin_amdgcn_mfma_f32_16x16x32_bf16(af0, bfr[j][0], acc[i][j], 0, 0, 0);
        acc[i][j] = __builtin_amdgcn_mfma_f32_16x16x32_bf16(af1, bfr[j][1], acc[i][j], 0, 0, 0);
      }
    }
    __builtin_amdgcn_s_setprio(0);
    cur ^= 1;
  }

  // epilogue
  #pragma unroll
  for (int i = 0; i < IR; ++i) {
    const int row0 = m0 + wr * (BM / 2) + i * 16 + lh * 4;
    #pragma unroll
    for (int j = 0; j < 4; ++j) {
      const int col = n0 + wc * 64 + j * 16 + lr;
      #pragma unroll
      for (int r = 0; r < 4; ++r) {
        const size_t idx = (size_t)(row0 + r) * N + col;
        if (BF16OUT)
          ((u16*)Cout)[idx] = f2bf_bits(acc[i][j][r]);
        else
          ((float*)Cout)[idx] = acc[i][j][r];
      }
    }
  }
}

// ---------------- flash attention v4: double-buffered K/V, one barrier/iter, bh-XCD swizzle ----------------
__global__ __launch_bounds__(256, 2) void attn_kernel(const u16* __restrict__ Q,
                                                      const u16* __restrict__ Kx,
                                                      const u16* __restrict__ Vt,
                                                      u16* __restrict__ O,
                                                      int S, int E, int H) {
  __shared__ __align__(16) u16 Ks[2][64 * 128];
  __shared__ __align__(16) u16 Vs[2][128 * 64];
  __shared__ __align__(16) u16 Pl[4][16 * 64];

  const int tid = threadIdx.x;
  const int wave = tid >> 6, lane = tid & 63;
  const int lr = lane & 15, lh = lane >> 4;
  // bh-clustered XCD mapping: xcd = bid&7 serves bh in {xcd, xcd+8, xcd+16, xcd+24};
  // concurrent working set per XCD ~3 bh x 1MB of K/V -> L2-resident.
  const int bid = blockIdx.x;               // 0..1023
  const int idx = bid >> 3;                 // 0..127
  const int bh = (bid & 7) + 8 * (idx >> 5);
  const int qb = idx & 31;
  const int b = bh / H, h = bh % H;
  const size_t base = ((size_t)b * S) * E + (size_t)h * 128;
  const u16* Qp = Q + base;
  const u16* Kp = Kx + base;
  const u16* Vp = Vt + (size_t)bh * 128 * S;
  u16* Op = O + base;

  const int qrow = qb * 64 + wave * 16 + lr;
  bf16x8 qf[4];
  #pragma unroll
  for (int c = 0; c < 4; ++c)
    qf[c] = *reinterpret_cast<const bf16x8*>(Qp + (size_t)qrow * E + c * 32 + lh * 8);

  // staging addresses (linear LDS dest + inverse-swizzled global source, rule 21)
  const int dstb = wave * 1024 + lane * 16;
  int ksrc[4], vsrc[4], ldso[4];
  #pragma unroll
  for (int i = 0; i < 4; ++i) {
    const int db = dstb + i * 4096;
    const int s = db >> 8;
    const int kcb = (db & 255) ^ ((s & 7) << 4);
    ksrc[i] = s * E + (kcb >> 1);
    const int d = db >> 7;
    const int vcb = (db & 127) ^ ((d & 7) << 4);
    vsrc[i] = d * S + (vcb >> 1);
    ldso[i] = (wave * 1024 + i * 4096) >> 1;
  }

  const f32x4 zf = {0.f, 0.f, 0.f, 0.f};
  f32x4 oacc[8];
  #pragma unroll
  for (int n = 0; n < 8; ++n) oacc[n] = zf;
  float Lp[4] = {0.f, 0.f, 0.f, 0.f};

  const float c2 = 0.12751649736230842f;  // log2(e)/sqrt(128)
  const int swz = (lr & 7) << 4;
  u16* pw = &Pl[wave][0];
  const int NT = S >> 6;

  // prologue: tile 0 -> buf 0
  #pragma unroll
  for (int i = 0; i < 4; ++i) gload_lds16(Kp + ksrc[i], &Ks[0][ldso[i]]);
  #pragma unroll
  for (int i = 0; i < 4; ++i) gload_lds16(Vp + vsrc[i], &Vs[0][ldso[i]]);

  int cur = 0;
  for (int t = 0; t < NT; ++t) {
    __syncthreads();   // drains vmcnt(0): buf[cur] staged; prev compute done (WAR safe)
    if (t + 1 < NT) {
      const int s0 = (t + 1) << 6;
      #pragma unroll
      for (int i = 0; i < 4; ++i) gload_lds16(Kp + s0 * E + ksrc[i], &Ks[cur ^ 1][ldso[i]]);
      #pragma unroll
      for (int i = 0; i < 4; ++i) gload_lds16(Vp + s0 + vsrc[i], &Vs[cur ^ 1][ldso[i]]);
    }

    f32x4 sg[4];
    #pragma unroll
    for (int g = 0; g < 4; ++g) sg[g] = zf;
    __builtin_amdgcn_s_setprio(1);
    #pragma unroll
    for (int c = 0; c < 4; ++c) {
      const int cb = (c * 64 + lh * 16) ^ swz;
      #pragma unroll
      for (int g = 0; g < 4; ++g) {
        bf16x8 kf = lds_read8(Ks[cur], (g * 16 + lr) * 256 + cb);
        sg[g] = __builtin_amdgcn_mfma_f32_16x16x32_bf16(qf[c], kf, sg[g], 0, 0, 0);
      }
    }
    __builtin_amdgcn_s_setprio(0);

    float p[4][4];
    #pragma unroll
    for (int g = 0; g < 4; ++g)
      #pragma unroll
      for (int j = 0; j < 4; ++j)
        p[g][j] = __builtin_exp2f(sg[g][j] * c2);
    #pragma unroll
    for (int j = 0; j < 4; ++j)
      Lp[j] += (p[0][j] + p[1][j]) + (p[2][j] + p[3][j]);

    #pragma unroll
    for (int j = 0; j < 4; ++j) {
      const int r = lh * 4 + j;
      const int rx = (r & 7) << 4;
      #pragma unroll
      for (int g = 0; g < 4; ++g) {
        const int cbp = ((g * 16 + lr) * 2) ^ rx;
        *reinterpret_cast<u16*>(reinterpret_cast<char*>(pw) + r * 128 + cbp) = f2bf_bits(p[g][j]);
      }
    }

    #pragma unroll
    for (int ks = 0; ks < 2; ++ks) {
      const int cb = ks * 64 + lh * 16;
      bf16x8 pf = lds_read8(pw, lr * 128 + (cb ^ swz));
      __builtin_amdgcn_s_setprio(1);
      #pragma unroll
      for (int n = 0; n < 8; ++n) {
        bf16x8 vf = lds_read8(Vs[cur], (n * 16 + lr) * 128 + (cb ^ swz));
        oacc[n] = __builtin_amdgcn_mfma_f32_16x16x32_bf16(pf, vf, oacc[n], 0, 0, 0);
      }
      __builtin_amdgcn_s_setprio(0);
    }
    cur ^= 1;
  }

  #pragma unroll
  for (int m = 1; m <= 8; m <<= 1)
    #pragma unroll
    for (int j = 0; j < 4; ++j)
      Lp[j] += __shfl_xor(Lp[j], m, 64);

  float inv[4];
  #pragma unroll
  for (int j = 0; j < 4; ++j) inv[j] = 1.0f / Lp[j];
  const int orow0 = qb * 64 + wave * 16 + lh * 4;
  #pragma unroll
  for (int n = 0; n < 8; ++n)
    #pragma unroll
    for (int j = 0; j < 4; ++j)
      Op[(size_t)(orow0 + j) * E + n * 16 + lr] = f2bf_bits(oacc[n][j] * inv[j]);
}

extern "C" void kernel_launch(void* const* d_in, const int* in_sizes, int n_in,
                              void* d_out, int out_size, void* d_ws, size_t ws_size,
                              hipStream_t stream) {
  const float* x    = (const float*)d_in[0];
  const float* rot  = (const float*)d_in[1];
  const float* ent  = (const float*)d_in[2];
  const float* wout = (const float*)d_in[3];
  const int B = 2, S = 2048, E = 2048, H = 16;
  const int M = B * S;                 // 4096
  const size_t nBSE = (size_t)M * E;   // 16 MB as bf16
  const size_t nEE = (size_t)E * E;    // 8 MB as bf16

  // ws: 3*nBSE u16 = 48 MB
  u16* xb = (u16*)d_ws;        // bf16 x; reused as ob after QK GEMM
  u16* qb = xb + nBSE;
  u16* kb = qb + nBSE;         // reused for bf16 w_out after attention
  // d_out (32 MB) as scratch until final GEMM: rb(8) + eb(8) + vt(16)
  u16* rb = (u16*)d_out;
  u16* eb = rb + nEE;
  u16* vt = eb + nEE;
  u16* wb = kb;
  u16* ob = xb;

  cast_bf16_kernel<<<(int)(nBSE / 4 / 256), 256, 0, stream>>>(x, xb, (int)(nBSE / 4));
  cast_bf16_kernel<<<(int)(nEE / 4 / 256), 256, 0, stream>>>(rot, rb, (int)(nEE / 4));
  cast_bf16_kernel<<<(int)(nEE / 4 / 256), 256, 0, stream>>>(ent, eb, (int)(nEE / 4));

  dim3 tg(S / 32, 128 / 32, B * H);
  build_vt_kernel<<<tg, 256, 0, stream>>>(x, vt, S, E, H);

  // fused Q+K projection: 256 wgs = 8 XCD clusters x 16 positions x 2 jobs
  gemm3_kernel<true, 256><<<256, 512, 0, stream>>>(xb, rb, eb, qb, kb, E, E, 1);

  attn_kernel<<<1024, 256, 0, stream>>>(qb, kb, vt, ob, S, E, H);

  cast_bf16_kernel<<<(int)(nEE / 4 / 256), 256, 0, stream>>>(wout, wb, (int)(nEE / 4));

  // output projection: 256 wgs (128x256 tiles) = full chip, fp32 out
  gemm3_kernel<false, 128><<<256, 512, 0, stream>>>(ob, wb, wb, d_out, d_out, E, E, 0);
}